// Round 1
// baseline (759.444 us; speedup 1.0000x reference)
//
#include <hip/hip_runtime.h>

#define DIM 4096
#define KVDIM 1024
#define SEQ 2048
#define HEADS 32
#define KVHEADS 8
#define HD 128

typedef __attribute__((ext_vector_type(8))) short bf16x8;
typedef __attribute__((ext_vector_type(4))) float f32x4;

__device__ inline unsigned short f2bf(float f) {
    union { float f; unsigned int u; } v; v.f = f;
    unsigned int r = v.u + 0x7fffu + ((v.u >> 16) & 1u);
    return (unsigned short)(r >> 16);
}
__device__ inline float bf2f(unsigned short h) {
    union { unsigned int u; float f; } v; v.u = ((unsigned int)h) << 16;
    return v.f;
}

// ---------------- f32 -> bf16 conversion (vectorized) ----------------
__global__ void convert_f32_bf16(const float* __restrict__ in,
                                 unsigned short* __restrict__ out, int n) {
    int i = (blockIdx.x * blockDim.x + threadIdx.x) * 8;
    if (i >= n) return;
    const float4* p = (const float4*)(in + i);
    float4 a = p[0], b = p[1];
    bf16x8 o;
    o[0] = (short)f2bf(a.x); o[1] = (short)f2bf(a.y);
    o[2] = (short)f2bf(a.z); o[3] = (short)f2bf(a.w);
    o[4] = (short)f2bf(b.x); o[5] = (short)f2bf(b.y);
    o[6] = (short)f2bf(b.z); o[7] = (short)f2bf(b.w);
    *(bf16x8*)(out + i) = o;
}

// ---------------- RoPE cos/sin table: [SEQ][64] ----------------
__global__ void rope_table(float* __restrict__ cs, float* __restrict__ sn) {
    int i = blockIdx.x * blockDim.x + threadIdx.x;
    if (i >= SEQ * 64) return;
    int m = i >> 6, f = i & 63;
    // freq = theta^(-2f/128) = exp(-f/64 * ln(10000))
    float freq = expf(-(float)f * (9.210340371976184f / 64.0f));
    float ang = (float)m * freq;
    float s, c;
    sincosf(ang, &s, &c);
    cs[i] = c; sn[i] = s;
}

// ---------------- RoPE apply in-place on bf16 buffer ----------------
// width = heads_of_buffer * 128; pairs (2i, 2i+1) within each head.
__global__ void rope_apply(unsigned short* __restrict__ q, int width,
                           const float* __restrict__ cs, const float* __restrict__ sn) {
    int i = blockIdx.x * blockDim.x + threadIdx.x;
    int pairs_per_row = width >> 1;
    if (i >= SEQ * pairs_per_row) return;
    int m = i / pairs_per_row;
    int p = i % pairs_per_row;
    int f = p & 63;                       // freq index within head
    int col = ((p >> 6) << 7) + (f << 1); // head*128 + 2f
    size_t idx = (size_t)m * width + col;
    unsigned int u = *(const unsigned int*)&q[idx];
    float xr = bf2f((unsigned short)(u & 0xffffu));
    float xi = bf2f((unsigned short)(u >> 16));
    float c = cs[(m << 6) + f], s = sn[(m << 6) + f];
    float orr = xr * c - xi * s;
    float oi  = xr * s + xi * c;
    unsigned int w = ((unsigned int)f2bf(oi) << 16) | (unsigned int)f2bf(orr);
    *(unsigned int*)&q[idx] = w;
}

// ---------------- GEMM: C(MxN) = A(MxK bf16) @ W(NxK f32)^T ----------------
#define BM 128
#define BN 128
#define BK 64
#define KPAD 8

template <bool OUT_BF16>
__global__ __launch_bounds__(256)
void gemm_bt(const unsigned short* __restrict__ A,
             const float* __restrict__ W,
             void* __restrict__ Cout,
             int M, int N, int K) {
    __shared__ __align__(16) unsigned short As[BM][BK + KPAD];
    __shared__ __align__(16) unsigned short Ws[BN][BK + KPAD];
    int tid = threadIdx.x;
    int lane = tid & 63, wid = tid >> 6;
    int wr = wid >> 1, wc = wid & 1;
    int l15 = lane & 15, lq = lane >> 4;
    int brow = blockIdx.y * BM, bcol = blockIdx.x * BN;

    f32x4 acc[4][4] = {};

    for (int bk = 0; bk < K; bk += BK) {
        // stage A (bf16): 128x64, 8 elems (16B) per thread per iter, 4 iters
        #pragma unroll
        for (int it = 0; it < 4; ++it) {
            int flat = it * 256 + tid;
            int r = flat >> 3, c = (flat & 7) * 8;
            *(bf16x8*)&As[r][c] =
                *(const bf16x8*)&A[(size_t)(brow + r) * K + bk + c];
        }
        // stage W (f32 -> bf16)
        #pragma unroll
        for (int it = 0; it < 4; ++it) {
            int flat = it * 256 + tid;
            int r = flat >> 3, c = (flat & 7) * 8;
            const float4* wp = (const float4*)&W[(size_t)(bcol + r) * K + bk + c];
            float4 w0 = wp[0], w1 = wp[1];
            bf16x8 t;
            t[0] = (short)f2bf(w0.x); t[1] = (short)f2bf(w0.y);
            t[2] = (short)f2bf(w0.z); t[3] = (short)f2bf(w0.w);
            t[4] = (short)f2bf(w1.x); t[5] = (short)f2bf(w1.y);
            t[6] = (short)f2bf(w1.z); t[7] = (short)f2bf(w1.w);
            *(bf16x8*)&Ws[r][c] = t;
        }
        __syncthreads();

        #pragma unroll
        for (int kk = 0; kk < BK; kk += 32) {
            bf16x8 af[4], bfr[4];
            #pragma unroll
            for (int m = 0; m < 4; ++m)
                af[m] = *(const bf16x8*)&As[wr * 64 + m * 16 + l15][kk + lq * 8];
            #pragma unroll
            for (int n = 0; n < 4; ++n)
                bfr[n] = *(const bf16x8*)&Ws[wc * 64 + n * 16 + l15][kk + lq * 8];
            #pragma unroll
            for (int m = 0; m < 4; ++m)
                #pragma unroll
                for (int n = 0; n < 4; ++n)
                    acc[m][n] = __builtin_amdgcn_mfma_f32_16x16x32_bf16(
                        af[m], bfr[n], acc[m][n], 0, 0, 0);
        }
        __syncthreads();
    }

    // epilogue: C/D layout col = lane&15, row = (lane>>4)*4 + r
    #pragma unroll
    for (int m = 0; m < 4; ++m) {
        #pragma unroll
        for (int n = 0; n < 4; ++n) {
            int row0 = brow + wr * 64 + m * 16 + lq * 4;
            int col = bcol + wc * 64 + n * 16 + l15;
            #pragma unroll
            for (int r = 0; r < 4; ++r) {
                if (OUT_BF16)
                    ((unsigned short*)Cout)[(size_t)(row0 + r) * N + col] = f2bf(acc[m][n][r]);
                else
                    ((float*)Cout)[(size_t)(row0 + r) * N + col] = acc[m][n][r];
            }
        }
    }
}

// ---------------- Flash attention (causal, GQA) ----------------
// grid: (HEADS, SEQ/QBLK); 256 threads = 4 waves; wave w owns 16 q-rows.
#define QBLK 64
#define KBLK 32

__global__ __launch_bounds__(256)
void attn_kernel(const unsigned short* __restrict__ Q,
                 const unsigned short* __restrict__ Kb,
                 const unsigned short* __restrict__ Vb,
                 unsigned short* __restrict__ O) {
    __shared__ __align__(16) unsigned short ks[KBLK][HD + KPAD];      // 32 x 136
    __shared__ __align__(16) unsigned short vt[HD][KBLK + KPAD];      // 128 x 40 (V^T)
    __shared__ __align__(16) unsigned short pl[4][16][KBLK + KPAD];   // per-wave P

    int h = blockIdx.x;
    int q0 = blockIdx.y * QBLK;
    int kvh = h >> 2;
    int tid = threadIdx.x, lane = tid & 63, wid = tid >> 6;
    int l15 = lane & 15, lq = lane >> 4;
    int qr = q0 + wid * 16;

    // Q fragments held in registers for the whole block
    bf16x8 qf[4];
    #pragma unroll
    for (int kk = 0; kk < 4; ++kk)
        qf[kk] = *(const bf16x8*)&Q[(size_t)(qr + l15) * DIM + h * HD + kk * 32 + lq * 8];

    f32x4 o_acc[8] = {};
    float m_run[4], l_run[4];
    #pragma unroll
    for (int r = 0; r < 4; ++r) { m_run[r] = -1e30f; l_run[r] = 0.0f; }

    const int kv_end = q0 + QBLK;
    for (int kv0 = 0; kv0 < kv_end; kv0 += KBLK) {
        // stage K tile row-major (coalesced)
        #pragma unroll
        for (int it = 0; it < 2; ++it) {
            int flat = it * 256 + tid;
            int r = flat >> 4, c = (flat & 15) * 8;
            *(bf16x8*)&ks[r][c] =
                *(const bf16x8*)&Kb[(size_t)(kv0 + r) * KVDIM + kvh * HD + c];
        }
        // stage V transposed: vt[n][k] = V[kv0+k][n]
        #pragma unroll
        for (int it = 0; it < 2; ++it) {
            int flat = it * 256 + tid;
            int k = flat >> 4, n0 = (flat & 15) * 8;
            bf16x8 v = *(const bf16x8*)&Vb[(size_t)(kv0 + k) * KVDIM + kvh * HD + n0];
            #pragma unroll
            for (int j = 0; j < 8; ++j)
                vt[n0 + j][k] = (unsigned short)v[j];
        }
        __syncthreads();

        // S = Q K^T  (16 q-rows x 32 kv)
        f32x4 s[2] = {};
        #pragma unroll
        for (int kk = 0; kk < 4; ++kk) {
            #pragma unroll
            for (int half = 0; half < 2; ++half) {
                bf16x8 kf = *(const bf16x8*)&ks[half * 16 + l15][kk * 32 + lq * 8];
                s[half] = __builtin_amdgcn_mfma_f32_16x16x32_bf16(qf[kk], kf, s[half], 0, 0, 0);
            }
        }

        // scale + causal mask
        const float scale = 0.08838834764831845f;
        #pragma unroll
        for (int half = 0; half < 2; ++half) {
            int colg = kv0 + half * 16 + l15;
            #pragma unroll
            for (int r = 0; r < 4; ++r) {
                int rowg = qr + lq * 4 + r;
                float v = s[half][r] * scale;
                s[half][r] = (colg > rowg) ? -1e30f : v;
            }
        }

        // online softmax (row groups are 16 lanes: xor masks 1,2,4,8)
        float p0[4], p1[4], alpha[4];
        #pragma unroll
        for (int r = 0; r < 4; ++r) {
            float mx = fmaxf(s[0][r], s[1][r]);
            mx = fmaxf(mx, __shfl_xor(mx, 1));
            mx = fmaxf(mx, __shfl_xor(mx, 2));
            mx = fmaxf(mx, __shfl_xor(mx, 4));
            mx = fmaxf(mx, __shfl_xor(mx, 8));
            float m_new = fmaxf(m_run[r], mx);
            alpha[r] = __expf(m_run[r] - m_new);
            m_run[r] = m_new;
            p0[r] = __expf(s[0][r] - m_new);
            p1[r] = __expf(s[1][r] - m_new);
            float sum = p0[r] + p1[r];
            sum += __shfl_xor(sum, 1);
            sum += __shfl_xor(sum, 2);
            sum += __shfl_xor(sum, 4);
            sum += __shfl_xor(sum, 8);
            l_run[r] = l_run[r] * alpha[r] + sum;
        }

        // rescale O
        #pragma unroll
        for (int t = 0; t < 8; ++t)
            #pragma unroll
            for (int r = 0; r < 4; ++r)
                o_acc[t][r] *= alpha[r];

        // P (D-layout) -> LDS -> A-fragment layout
        #pragma unroll
        for (int r = 0; r < 4; ++r) {
            pl[wid][lq * 4 + r][l15] = f2bf(p0[r]);
            pl[wid][lq * 4 + r][16 + l15] = f2bf(p1[r]);
        }
        asm volatile("s_waitcnt lgkmcnt(0)" ::: "memory");
        bf16x8 pf = *(const bf16x8*)&pl[wid][l15][lq * 8];

        // O += P @ V  (8 output 16-col tiles)
        #pragma unroll
        for (int t = 0; t < 8; ++t) {
            bf16x8 vf = *(const bf16x8*)&vt[t * 16 + l15][lq * 8];
            o_acc[t] = __builtin_amdgcn_mfma_f32_16x16x32_bf16(pf, vf, o_acc[t], 0, 0, 0);
        }
        __syncthreads();
    }

    // normalize + store
    #pragma unroll
    for (int t = 0; t < 8; ++t) {
        #pragma unroll
        for (int r = 0; r < 4; ++r) {
            int rowg = qr + lq * 4 + r;
            int colg = h * HD + t * 16 + l15;
            O[(size_t)rowg * DIM + colg] = f2bf(o_acc[t][r] / l_run[r]);
        }
    }
}

// ---------------- host ----------------
extern "C" void kernel_launch(void* const* d_in, const int* in_sizes, int n_in,
                              void* d_out, int out_size, void* d_ws, size_t ws_size,
                              hipStream_t stream) {
    const float* x  = (const float*)d_in[0];
    const float* wq = (const float*)d_in[2];
    const float* wk = (const float*)d_in[3];
    const float* wv = (const float*)d_in[4];
    const float* wo = (const float*)d_in[5];
    float* out = (float*)d_out;

    char* ws = (char*)d_ws;
    unsigned short* xb = (unsigned short*)(ws);                    // 16 MiB
    unsigned short* qb = (unsigned short*)(ws + 16777216);         // 16 MiB
    unsigned short* kb = (unsigned short*)(ws + 33554432);         //  4 MiB
    unsigned short* vb = (unsigned short*)(ws + 37748736);         //  4 MiB
    unsigned short* ab = (unsigned short*)(ws + 41943040);         // 16 MiB
    float* cs = (float*)(ws + 58720256);                           // SEQ*64 f32
    float* sn = cs + SEQ * 64;

    convert_f32_bf16<<<(SEQ * DIM / 8 + 255) / 256, 256, 0, stream>>>(x, xb, SEQ * DIM);
    rope_table<<<(SEQ * 64 + 255) / 256, 256, 0, stream>>>(cs, sn);

    gemm_bt<true><<<dim3(DIM / BN, SEQ / BM), 256, 0, stream>>>(xb, wq, qb, SEQ, DIM, DIM);
    gemm_bt<true><<<dim3(KVDIM / BN, SEQ / BM), 256, 0, stream>>>(xb, wk, kb, SEQ, KVDIM, DIM);
    gemm_bt<true><<<dim3(KVDIM / BN, SEQ / BM), 256, 0, stream>>>(xb, wv, vb, SEQ, KVDIM, DIM);

    rope_apply<<<(SEQ * (DIM / 2) + 255) / 256, 256, 0, stream>>>(qb, DIM, cs, sn);
    rope_apply<<<(SEQ * (KVDIM / 2) + 255) / 256, 256, 0, stream>>>(kb, KVDIM, cs, sn);

    attn_kernel<<<dim3(HEADS, SEQ / QBLK), 256, 0, stream>>>(qb, kb, vb, ab);

    gemm_bt<false><<<dim3(DIM / BN, SEQ / BM), 256, 0, stream>>>(ab, wo, out, SEQ, DIM, DIM);
}

// Round 2
// 443.660 us; speedup vs baseline: 1.7118x; 1.7118x over previous
//
#include <hip/hip_runtime.h>

#define DIM 4096
#define KVDIM 1024
#define KVSTRIDE 2048
#define SEQ 2048
#define HEADS 32
#define HD 128

typedef __attribute__((ext_vector_type(8))) short bf16x8;
typedef __attribute__((ext_vector_type(4))) float f32x4;

__device__ inline unsigned short f2bf(float f) {
    union { float f; unsigned int u; } v; v.f = f;
    unsigned int r = v.u + 0x7fffu + ((v.u >> 16) & 1u);
    return (unsigned short)(r >> 16);
}
__device__ inline float bf2f(unsigned short h) {
    union { unsigned int u; float f; } v; v.u = ((unsigned int)h) << 16;
    return v.f;
}

// async global->LDS, 16B per lane; LDS dest is wave-uniform base + lane*16
__device__ inline void gld16(const void* g, void* l) {
    __builtin_amdgcn_global_load_lds(
        (const __attribute__((address_space(1))) void*)g,
        (__attribute__((address_space(3))) void*)l, 16, 0, 0);
}

// ---------------- f32 -> bf16 conversion (vectorized) ----------------
__global__ void convert_f32_bf16(const float* __restrict__ in,
                                 unsigned short* __restrict__ out, int n) {
    int i = (blockIdx.x * blockDim.x + threadIdx.x) * 8;
    if (i >= n) return;
    const float4* p = (const float4*)(in + i);
    float4 a = p[0], b = p[1];
    bf16x8 o;
    o[0] = (short)f2bf(a.x); o[1] = (short)f2bf(a.y);
    o[2] = (short)f2bf(a.z); o[3] = (short)f2bf(a.w);
    o[4] = (short)f2bf(b.x); o[5] = (short)f2bf(b.y);
    o[6] = (short)f2bf(b.z); o[7] = (short)f2bf(b.w);
    *(bf16x8*)(out + i) = o;
}

// ---------------- RoPE cos/sin table: [SEQ][64] ----------------
__global__ void rope_table(float* __restrict__ cs, float* __restrict__ sn) {
    int i = blockIdx.x * blockDim.x + threadIdx.x;
    if (i >= SEQ * 64) return;
    int m = i >> 6, f = i & 63;
    float freq = expf(-(float)f * (9.210340371976184f / 64.0f));
    float ang = (float)m * freq;
    float s, c;
    sincosf(ang, &s, &c);
    cs[i] = c; sn[i] = s;
}

// ---------------- RoPE apply in-place (bf16), optional output scale ----------------
__global__ void rope_apply(unsigned short* __restrict__ q, int lppr, int stride, float scale,
                           const float* __restrict__ cs, const float* __restrict__ sn) {
    int i = blockIdx.x * blockDim.x + threadIdx.x;
    int m = i >> lppr;
    int p = i & ((1 << lppr) - 1);
    if (m >= SEQ) return;
    int f = p & 63;
    int col = ((p >> 6) << 7) + (f << 1);
    size_t idx = (size_t)m * stride + col;
    unsigned int u = *(const unsigned int*)&q[idx];
    float xr = bf2f((unsigned short)(u & 0xffffu));
    float xi = bf2f((unsigned short)(u >> 16));
    float c = cs[(m << 6) + f], s = sn[(m << 6) + f];
    float orr = (xr * c - xi * s) * scale;
    float oi  = (xr * s + xi * c) * scale;
    unsigned int w = ((unsigned int)f2bf(oi) << 16) | (unsigned int)f2bf(orr);
    *(unsigned int*)&q[idx] = w;
}

// ---------------- GEMM: C(MxN) = A(MxK bf16) @ W(NxK bf16)^T ----------------
// m97 structure: 128x128 tile, BK=64, global_load_lds(16B) staging into linear
// LDS with granule swizzle g' = g ^ (row&7) (inverse-swizzled global source).
template <bool OUT_BF16>
__global__ __launch_bounds__(256)
void gemm_bt(const unsigned short* __restrict__ A,
             const unsigned short* __restrict__ W,
             void* __restrict__ Cout, int M, int N, int K) {
    __shared__ __align__(16) unsigned short As[128 * 64];
    __shared__ __align__(16) unsigned short Ws[128 * 64];

    // bijective XCD swizzle (nwg is a multiple of 8 for all our grids)
    int nwg = gridDim.x * gridDim.y;
    int wg = blockIdx.y * gridDim.x + blockIdx.x;
    int cpx = nwg >> 3;
    wg = (wg & 7) * cpx + (wg >> 3);
    int bx = wg % gridDim.x, by = wg / gridDim.x;
    int brow = by * 128, bcol = bx * 128;

    int tid = threadIdx.x, lane = tid & 63, wid = tid >> 6;
    int wr = wid >> 1, wc = wid & 1, l15 = lane & 15, lq = lane >> 4;

    f32x4 acc[4][4] = {};

    for (int bk = 0; bk < K; bk += 64) {
        // stage A and W: 128 rows x 8 granules(16B) each = 1024 slots apiece
        #pragma unroll
        for (int it = 0; it < 4; ++it) {
            int slot = it * 256 + wid * 64 + lane;
            int r = slot >> 3, g = slot & 7;
            gld16(&A[(size_t)(brow + r) * K + bk + ((g ^ (r & 7)) << 3)],
                  &As[(it * 256 + wid * 64) * 8]);
        }
        #pragma unroll
        for (int it = 0; it < 4; ++it) {
            int slot = it * 256 + wid * 64 + lane;
            int r = slot >> 3, g = slot & 7;
            gld16(&W[(size_t)(bcol + r) * K + bk + ((g ^ (r & 7)) << 3)],
                  &Ws[(it * 256 + wid * 64) * 8]);
        }
        __syncthreads();

        #pragma unroll
        for (int kk = 0; kk < 64; kk += 32) {
            int gb = (kk >> 3) + lq;
            bf16x8 af[4], bfr[4];
            #pragma unroll
            for (int m = 0; m < 4; ++m) {
                int r = wr * 64 + m * 16 + l15;
                af[m] = *(const bf16x8*)&As[r * 64 + ((gb ^ (r & 7)) << 3)];
            }
            #pragma unroll
            for (int n = 0; n < 4; ++n) {
                int r = wc * 64 + n * 16 + l15;
                bfr[n] = *(const bf16x8*)&Ws[r * 64 + ((gb ^ (r & 7)) << 3)];
            }
            #pragma unroll
            for (int m = 0; m < 4; ++m)
                #pragma unroll
                for (int n = 0; n < 4; ++n)
                    acc[m][n] = __builtin_amdgcn_mfma_f32_16x16x32_bf16(
                        af[m], bfr[n], acc[m][n], 0, 0, 0);
        }
        __syncthreads();
    }

    #pragma unroll
    for (int m = 0; m < 4; ++m) {
        #pragma unroll
        for (int n = 0; n < 4; ++n) {
            int row0 = brow + wr * 64 + m * 16 + lq * 4;
            int col = bcol + wc * 64 + n * 16 + l15;
            #pragma unroll
            for (int r = 0; r < 4; ++r) {
                if (OUT_BF16)
                    ((unsigned short*)Cout)[(size_t)(row0 + r) * N + col] = f2bf(acc[m][n][r]);
                else
                    ((float*)Cout)[(size_t)(row0 + r) * N + col] = acc[m][n][r];
            }
        }
    }
}

// ---------------- Flash attention (causal, GQA) ----------------
// QBLK=128 (4 waves x 32 rows), KBLK=64. Q pre-scaled by 1/sqrt(hd)*log2(e)
// in rope_apply, so softmax runs in exp2 domain. LPT dispatch: longest
// (diag-heavy) blocks first. K via global_load_lds+swizzle; V^T reg-staged
// with granule XOR swizzle; P round-trips per-wave LDS with row-keyed swizzle.
__global__ __launch_bounds__(256)
void attn_kernel(const unsigned short* __restrict__ Q,
                 const unsigned short* __restrict__ KV,
                 unsigned short* __restrict__ O) {
    __shared__ __align__(16) unsigned short ks[64 * 128];     // 16 KB, linear, swizzled
    __shared__ __align__(16) unsigned short vt[128][72];      // 18 KB, V^T swizzled
    __shared__ __align__(16) unsigned short pl[4][32][72];    // 18 KB, per-wave P

    int h = blockIdx.x;
    int yy = (gridDim.y - 1) - blockIdx.y;   // reversed: longest blocks dispatch first
    int q0 = yy * 128;
    int kvh = h >> 2;
    int tid = threadIdx.x, lane = tid & 63, wid = tid >> 6;
    int l15 = lane & 15, lq = lane >> 4;
    int qr0 = q0 + wid * 32;

    // Q fragments: 2 row-frags x 4 k-steps, held all kernel
    bf16x8 qf[2][4];
    #pragma unroll
    for (int rf = 0; rf < 2; ++rf)
        #pragma unroll
        for (int k4 = 0; k4 < 4; ++k4)
            qf[rf][k4] = *(const bf16x8*)&Q[(size_t)(qr0 + rf * 16 + l15) * DIM + h * HD + k4 * 32 + lq * 8];

    f32x4 o_acc[2][8] = {};
    float m_run[2][4], l_run[2][4];
    #pragma unroll
    for (int rf = 0; rf < 2; ++rf)
        #pragma unroll
        for (int r = 0; r < 4; ++r) { m_run[rf][r] = -1e30f; l_run[rf][r] = 0.0f; }

    int ntiles = (q0 + 128) >> 6;
    for (int t64 = 0; t64 < ntiles; ++t64) {
        int kv0 = t64 * 64;
        // K tile: 64 rows x 16 granules, global_load_lds with inverse swizzle
        #pragma unroll
        for (int it = 0; it < 4; ++it) {
            int slot = it * 256 + wid * 64 + lane;
            int r = slot >> 4, g = slot & 15;
            gld16(&KV[(size_t)(kv0 + r) * KVSTRIDE + kvh * HD + ((g ^ (r & 7)) << 3)],
                  &ks[(it * 256 + wid * 64) * 8]);
        }
        // V^T staging with granule swizzle (write banks spread by l15&7)
        #pragma unroll
        for (int it = 0; it < 4; ++it) {
            int flat = it * 256 + tid;
            int k = flat >> 4, d0 = (flat & 15) << 3;
            bf16x8 v = *(const bf16x8*)&KV[(size_t)(kv0 + k) * KVSTRIDE + KVDIM + kvh * HD + d0];
            int swz = flat & 7;           // = (d>>3)&7 for this thread's 8 d's
            int cbase = (((k >> 3) ^ swz) << 3) | (k & 7);
            #pragma unroll
            for (int j = 0; j < 8; ++j)
                vt[d0 + j][cbase] = (unsigned short)v[j];
        }
        __syncthreads();

        if (kv0 <= qr0 + 31) {   // wave-uniform: skip fully-masked tiles
            f32x4 s[2][4] = {};
            // S = Q K^T : kf read once, feeds both row-frags
            #pragma unroll
            for (int k4 = 0; k4 < 4; ++k4)
                #pragma unroll
                for (int c = 0; c < 4; ++c) {
                    int r = c * 16 + l15;
                    bf16x8 kf = *(const bf16x8*)&ks[r * 128 + ((((k4 << 2) + lq) ^ (r & 7)) << 3)];
                    s[0][c] = __builtin_amdgcn_mfma_f32_16x16x32_bf16(qf[0][k4], kf, s[0][c], 0, 0, 0);
                    s[1][c] = __builtin_amdgcn_mfma_f32_16x16x32_bf16(qf[1][k4], kf, s[1][c], 0, 0, 0);
                }

            #pragma unroll
            for (int rf = 0; rf < 2; ++rf) {
                int qrf = qr0 + rf * 16;
                if (kv0 + 63 > qrf) {  // diagonal tile: apply causal mask
                    #pragma unroll
                    for (int c = 0; c < 4; ++c) {
                        int colg = kv0 + c * 16 + l15;
                        #pragma unroll
                        for (int r = 0; r < 4; ++r) {
                            int rowg = qrf + lq * 4 + r;
                            if (colg > rowg) s[rf][c][r] = -1e30f;
                        }
                    }
                }
                // per-row max (16-lane groups), defer-max skip (THR=8 log2)
                float mx[4];
                bool need = false;
                #pragma unroll
                for (int r = 0; r < 4; ++r) {
                    float e = fmaxf(fmaxf(s[rf][0][r], s[rf][1][r]),
                                    fmaxf(s[rf][2][r], s[rf][3][r]));
                    e = fmaxf(e, __shfl_xor(e, 1));
                    e = fmaxf(e, __shfl_xor(e, 2));
                    e = fmaxf(e, __shfl_xor(e, 4));
                    e = fmaxf(e, __shfl_xor(e, 8));
                    mx[r] = e;
                    need = need || (e > m_run[rf][r] + 8.0f);
                }
                if (__any((int)need)) {
                    #pragma unroll
                    for (int r = 0; r < 4; ++r) {
                        float mn = fmaxf(m_run[rf][r], mx[r]);
                        float al = exp2f(m_run[rf][r] - mn);
                        m_run[rf][r] = mn;
                        l_run[rf][r] *= al;
                        #pragma unroll
                        for (int t = 0; t < 8; ++t) o_acc[rf][t][r] *= al;
                    }
                }
                // P = exp2(s - m); per-lane partial l; store to pl (swizzled)
                #pragma unroll
                for (int c = 0; c < 4; ++c)
                    #pragma unroll
                    for (int r = 0; r < 4; ++r) {
                        float p = exp2f(s[rf][c][r] - m_run[rf][r]);
                        l_run[rf][r] += p;
                        int prow = rf * 16 + lq * 4 + r;
                        int pcol = (c * 16 + l15) ^ (((lq * 4 + r) & 7) << 3);
                        pl[wid][prow][pcol] = (unsigned short)(__float_as_uint(p) >> 16);
                    }
            }
            asm volatile("s_waitcnt lgkmcnt(0)" ::: "memory");

            // O += P @ V
            #pragma unroll
            for (int kk2 = 0; kk2 < 2; ++kk2) {
                bf16x8 pf[2];
                #pragma unroll
                for (int rf = 0; rf < 2; ++rf)
                    pf[rf] = *(const bf16x8*)&pl[wid][rf * 16 + l15]
                                               [(((kk2 << 2) + lq) ^ (l15 & 7)) << 3];
                #pragma unroll
                for (int t = 0; t < 8; ++t) {
                    int d = t * 16 + l15;
                    bf16x8 vf = *(const bf16x8*)&vt[d][(((kk2 << 2) + lq) ^ ((d >> 3) & 7)) << 3];
                    o_acc[0][t] = __builtin_amdgcn_mfma_f32_16x16x32_bf16(pf[0], vf, o_acc[0][t], 0, 0, 0);
                    o_acc[1][t] = __builtin_amdgcn_mfma_f32_16x16x32_bf16(pf[1], vf, o_acc[1][t], 0, 0, 0);
                }
            }
        }
        __syncthreads();
    }

    // finalize: reduce per-lane l across 16-lane groups, normalize, store bf16
    #pragma unroll
    for (int rf = 0; rf < 2; ++rf) {
        float rl[4];
        #pragma unroll
        for (int r = 0; r < 4; ++r) {
            float x = l_run[rf][r];
            x += __shfl_xor(x, 1);
            x += __shfl_xor(x, 2);
            x += __shfl_xor(x, 4);
            x += __shfl_xor(x, 8);
            rl[r] = __builtin_amdgcn_rcpf(x);
        }
        #pragma unroll
        for (int t = 0; t < 8; ++t)
            #pragma unroll
            for (int r = 0; r < 4; ++r)
                O[(size_t)(qr0 + rf * 16 + lq * 4 + r) * DIM + h * HD + t * 16 + l15] =
                    f2bf(o_acc[rf][t][r] * rl[r]);
    }
}

// ---------------- host ----------------
extern "C" void kernel_launch(void* const* d_in, const int* in_sizes, int n_in,
                              void* d_out, int out_size, void* d_ws, size_t ws_size,
                              hipStream_t stream) {
    const float* x  = (const float*)d_in[0];
    const float* wq = (const float*)d_in[2];
    const float* wk = (const float*)d_in[3];
    const float* wv = (const float*)d_in[4];
    const float* wo = (const float*)d_in[5];
    float* out = (float*)d_out;

    char* ws = (char*)d_ws;
    unsigned short* xb  = (unsigned short*)(ws);               // 16 MiB
    unsigned short* qb  = (unsigned short*)(ws + 16777216);    // 16 MiB
    unsigned short* kvb = (unsigned short*)(ws + 33554432);    //  8 MiB (K|V packed, stride 2048)
    unsigned short* ab  = (unsigned short*)(ws + 41943040);    // 16 MiB
    float* cs = (float*)(ws + 58720256);                       // 512 KiB
    float* sn = cs + SEQ * 64;                                 // 512 KiB
    // weight staging: wq/wkv go through d_out (dead until final GEMM);
    // wo goes into ws[0..32M) (xb+qb region, dead after attn).
    unsigned short* wscratch = (unsigned short*)d_out;
    unsigned short* wob = (unsigned short*)(ws);

    const float SCALE2 = 0.08838834764831845f * 1.4426950408889634f; // 1/sqrt(128)*log2(e)

    convert_f32_bf16<<<SEQ * DIM / 2048, 256, 0, stream>>>(x, xb, SEQ * DIM);
    rope_table<<<SEQ * 64 / 256, 256, 0, stream>>>(cs, sn);

    // Q projection
    convert_f32_bf16<<<DIM * DIM / 2048, 256, 0, stream>>>(wq, wscratch, DIM * DIM);
    gemm_bt<true><<<dim3(DIM / 128, SEQ / 128), 256, 0, stream>>>(xb, wscratch, qb, SEQ, DIM, DIM);

    // K,V projection packed into one N=2048 GEMM
    convert_f32_bf16<<<KVDIM * DIM / 2048, 256, 0, stream>>>(wk, wscratch, KVDIM * DIM);
    convert_f32_bf16<<<KVDIM * DIM / 2048, 256, 0, stream>>>(wv, wscratch + (size_t)KVDIM * DIM, KVDIM * DIM);
    gemm_bt<true><<<dim3(KVSTRIDE / 128, SEQ / 128), 256, 0, stream>>>(xb, wscratch, kvb, SEQ, KVSTRIDE, DIM);

    // RoPE: Q gets softmax scale folded in (exp2-domain attention)
    rope_apply<<<SEQ * (DIM / 2) / 256, 256, 0, stream>>>(qb, 11, DIM, SCALE2, cs, sn);
    rope_apply<<<SEQ * (KVDIM / 2) / 256, 256, 0, stream>>>(kvb, 9, KVSTRIDE, 1.0f, cs, sn);

    attn_kernel<<<dim3(HEADS, SEQ / 128), 256, 0, stream>>>(qb, kvb, ab);

    // O projection (wo converted into now-dead xb/qb region)
    convert_f32_bf16<<<DIM * DIM / 2048, 256, 0, stream>>>(wo, wob, DIM * DIM);
    gemm_bt<false><<<dim3(DIM / 128, SEQ / 128), 256, 0, stream>>>(ab, wob, out, SEQ, DIM, DIM);
}

// Round 4
// 397.942 us; speedup vs baseline: 1.9084x; 1.1149x over previous
//
#include <hip/hip_runtime.h>

#define DIM 4096
#define KVDIM 1024
#define KVSTRIDE 2048
#define SEQ 2048
#define HEADS 32
#define HD 128

typedef __attribute__((ext_vector_type(8))) short bf16x8;
typedef __attribute__((ext_vector_type(4))) float f32x4;
typedef __attribute__((ext_vector_type(16))) float f32x16;
typedef __attribute__((ext_vector_type(4))) int int4v;

__device__ inline unsigned short f2bf(float f) {
    union { float f; unsigned int u; } v; v.f = f;
    unsigned int r = v.u + 0x7fffu + ((v.u >> 16) & 1u);
    return (unsigned short)(r >> 16);
}
__device__ inline float bf2f(unsigned short h) {
    union { unsigned int u; float f; } v; v.u = ((unsigned int)h) << 16;
    return v.f;
}

// async global->LDS, 16B per lane; LDS dest is wave-uniform base + lane*16
__device__ inline void gld16(const void* g, void* l) {
    __builtin_amdgcn_global_load_lds(
        (const __attribute__((address_space(1))) void*)g,
        (__attribute__((address_space(3))) void*)l, 16, 0, 0);
}

// v_cvt_pk_bf16_f32: lo=bf16(a), hi=bf16(b)
__device__ inline unsigned cvtpk(float a, float b) {
    unsigned r;
    asm("v_cvt_pk_bf16_f32 %0, %1, %2" : "=v"(r) : "v"(a), "v"(b));
    return r;
}

// ---------------- f32 -> bf16 conversion (vectorized) ----------------
__global__ void convert_f32_bf16(const float* __restrict__ in,
                                 unsigned short* __restrict__ out, int n) {
    int i = (blockIdx.x * blockDim.x + threadIdx.x) * 8;
    if (i >= n) return;
    const float4* p = (const float4*)(in + i);
    float4 a = p[0], b = p[1];
    bf16x8 o;
    o[0] = (short)f2bf(a.x); o[1] = (short)f2bf(a.y);
    o[2] = (short)f2bf(a.z); o[3] = (short)f2bf(a.w);
    o[4] = (short)f2bf(b.x); o[5] = (short)f2bf(b.y);
    o[6] = (short)f2bf(b.z); o[7] = (short)f2bf(b.w);
    *(bf16x8*)(out + i) = o;
}

// ---------------- RoPE cos/sin table: [SEQ][64] ----------------
__global__ void rope_table(float* __restrict__ cs, float* __restrict__ sn) {
    int i = blockIdx.x * blockDim.x + threadIdx.x;
    if (i >= SEQ * 64) return;
    int m = i >> 6, f = i & 63;
    float freq = expf(-(float)f * (9.210340371976184f / 64.0f));
    float ang = (float)m * freq;
    float s, c;
    sincosf(ang, &s, &c);
    cs[i] = c; sn[i] = s;
}

// ---------------- RoPE apply in-place (bf16), optional output scale ----------------
__global__ void rope_apply(unsigned short* __restrict__ q, int lppr, int stride, float scale,
                           const float* __restrict__ cs, const float* __restrict__ sn) {
    int i = blockIdx.x * blockDim.x + threadIdx.x;
    int m = i >> lppr;
    int p = i & ((1 << lppr) - 1);
    if (m >= SEQ) return;
    int f = p & 63;
    int col = ((p >> 6) << 7) + (f << 1);
    size_t idx = (size_t)m * stride + col;
    unsigned int u = *(const unsigned int*)&q[idx];
    float xr = bf2f((unsigned short)(u & 0xffffu));
    float xi = bf2f((unsigned short)(u >> 16));
    float c = cs[(m << 6) + f], s = sn[(m << 6) + f];
    float orr = (xr * c - xi * s) * scale;
    float oi  = (xr * s + xi * c) * scale;
    unsigned int w = ((unsigned int)f2bf(oi) << 16) | (unsigned int)f2bf(orr);
    *(unsigned int*)&q[idx] = w;
}

// ---------------- GEMM: C(MxN) = A(MxK bf16) @ W(NxK bf16)^T ----------------
template <bool OUT_BF16>
__global__ __launch_bounds__(256)
void gemm_bt(const unsigned short* __restrict__ A,
             const unsigned short* __restrict__ W,
             void* __restrict__ Cout, int M, int N, int K) {
    __shared__ __align__(16) unsigned short As[128 * 64];
    __shared__ __align__(16) unsigned short Ws[128 * 64];

    int nwg = gridDim.x * gridDim.y;
    int wg = blockIdx.y * gridDim.x + blockIdx.x;
    int cpx = nwg >> 3;
    wg = (wg & 7) * cpx + (wg >> 3);
    int bx = wg % gridDim.x, by = wg / gridDim.x;
    int brow = by * 128, bcol = bx * 128;

    int tid = threadIdx.x, lane = tid & 63, wid = tid >> 6;
    int wr = wid >> 1, wc = wid & 1, l15 = lane & 15, lq = lane >> 4;

    f32x4 acc[4][4] = {};

    for (int bk = 0; bk < K; bk += 64) {
        #pragma unroll
        for (int it = 0; it < 4; ++it) {
            int slot = it * 256 + wid * 64 + lane;
            int r = slot >> 3, g = slot & 7;
            gld16(&A[(size_t)(brow + r) * K + bk + ((g ^ (r & 7)) << 3)],
                  &As[(it * 256 + wid * 64) * 8]);
        }
        #pragma unroll
        for (int it = 0; it < 4; ++it) {
            int slot = it * 256 + wid * 64 + lane;
            int r = slot >> 3, g = slot & 7;
            gld16(&W[(size_t)(bcol + r) * K + bk + ((g ^ (r & 7)) << 3)],
                  &Ws[(it * 256 + wid * 64) * 8]);
        }
        __syncthreads();

        #pragma unroll
        for (int kk = 0; kk < 64; kk += 32) {
            int gb = (kk >> 3) + lq;
            bf16x8 af[4], bfr[4];
            #pragma unroll
            for (int m = 0; m < 4; ++m) {
                int r = wr * 64 + m * 16 + l15;
                af[m] = *(const bf16x8*)&As[r * 64 + ((gb ^ (r & 7)) << 3)];
            }
            #pragma unroll
            for (int n = 0; n < 4; ++n) {
                int r = wc * 64 + n * 16 + l15;
                bfr[n] = *(const bf16x8*)&Ws[r * 64 + ((gb ^ (r & 7)) << 3)];
            }
            #pragma unroll
            for (int m = 0; m < 4; ++m)
                #pragma unroll
                for (int n = 0; n < 4; ++n)
                    acc[m][n] = __builtin_amdgcn_mfma_f32_16x16x32_bf16(
                        af[m], bfr[n], acc[m][n], 0, 0, 0);
        }
        __syncthreads();
    }

    #pragma unroll
    for (int m = 0; m < 4; ++m) {
        #pragma unroll
        for (int n = 0; n < 4; ++n) {
            int row0 = brow + wr * 64 + m * 16 + lq * 4;
            int col = bcol + wc * 64 + n * 16 + l15;
            #pragma unroll
            for (int r = 0; r < 4; ++r) {
                if (OUT_BF16)
                    ((unsigned short*)Cout)[(size_t)(row0 + r) * N + col] = f2bf(acc[m][n][r]);
                else
                    ((float*)Cout)[(size_t)(row0 + r) * N + col] = acc[m][n][r];
            }
        }
    }
}

// ---------------- Flash attention: 32x32 swapped-QK^T, in-register softmax ----
// 4 waves x 32 q-rows (QBLK=128), KBLK=64. S^T = mfma(K,Q): q = lane&31, so
// softmax is register-local + one shfl_xor(32). P->A-frag via cvt_pk + bit5
// exchange. V staged TRANSPOSED into vt[d][kv] (stride 66: reads 2-way/free)
// via in-register 4x8 transpose + packed b32 writes. No tr-read, no P-LDS.
__global__ __launch_bounds__(256)
void attn_kernel(const unsigned short* __restrict__ Q,
                 const unsigned short* __restrict__ KV,
                 unsigned short* __restrict__ O) {
    __shared__ __align__(16) unsigned short ks[64 * 128];   // 16 KB, granule-XOR
    __shared__ __align__(16) unsigned short vt[128][66];    // 16.5 KB, V^T

    int h = blockIdx.x;
    int yy = (gridDim.y - 1) - blockIdx.y;   // LPT: longest blocks first
    int q0 = yy * 128;
    int kvh = h >> 2;
    int tid = threadIdx.x, lane = tid & 63, wid = tid >> 6;
    int l31 = lane & 31, l5 = lane >> 5;
    int qw0 = q0 + wid * 32;

    // Q fragments (B-operand): qf[k8] = Q[qw0+l31][h*128 + k8*16 + l5*8 ..]
    bf16x8 qf[8];
    #pragma unroll
    for (int k8 = 0; k8 < 8; ++k8)
        qf[k8] = *(const bf16x8*)&Q[(size_t)(qw0 + l31) * DIM + h * HD + k8 * 16 + l5 * 8];

    f32x16 o_acc[4] = {};
    float m_run = -1e30f, l_run = 0.0f;

    // V staging decomposition: thread stages 4 kv-rows x 8 d's
    int k4 = tid >> 4;            // [0,16) -> kv = k4*4 .. +4
    int d0 = (tid & 15) * 8;      // [0,128)

    int ntiles = (q0 + 128) >> 6;
    for (int t = 0; t < ntiles; ++t) {
        int kv0 = t * 64;
        // K: 64 rows x 16 granules(8 bf16), inverse-swizzled source
        #pragma unroll
        for (int it = 0; it < 4; ++it) {
            int slot = it * 256 + wid * 64 + lane;
            int r = slot >> 4, g = slot & 15;
            gld16(&KV[(size_t)(kv0 + r) * KVSTRIDE + kvh * HD + ((g ^ (r & 7)) << 3)],
                  &ks[(it * 256 + wid * 64) * 8]);
        }
        // V: load 4 rows x 8 cols, transpose in regs, packed b32 writes
        {
            bf16x8 v0 = *(const bf16x8*)&KV[(size_t)(kv0 + k4 * 4 + 0) * KVSTRIDE + KVDIM + kvh * HD + d0];
            bf16x8 v1 = *(const bf16x8*)&KV[(size_t)(kv0 + k4 * 4 + 1) * KVSTRIDE + KVDIM + kvh * HD + d0];
            bf16x8 v2 = *(const bf16x8*)&KV[(size_t)(kv0 + k4 * 4 + 2) * KVSTRIDE + KVDIM + kvh * HD + d0];
            bf16x8 v3 = *(const bf16x8*)&KV[(size_t)(kv0 + k4 * 4 + 3) * KVSTRIDE + KVDIM + kvh * HD + d0];
            #pragma unroll
            for (int j = 0; j < 8; ++j) {
                unsigned lo = ((unsigned)(unsigned short)v1[j] << 16) | (unsigned)(unsigned short)v0[j];
                unsigned hi = ((unsigned)(unsigned short)v3[j] << 16) | (unsigned)(unsigned short)v2[j];
                *(unsigned*)&vt[d0 + j][k4 * 4]     = lo;
                *(unsigned*)&vt[d0 + j][k4 * 4 + 2] = hi;
            }
        }
        __syncthreads();

        if (kv0 <= qw0 + 31) {
            #pragma unroll
            for (int sub = 0; sub < 2; ++sub) {
                int kvs = kv0 + sub * 32;
                if (kvs > qw0 + 31) continue;   // wave-uniform: fully masked
                // S^T = K @ Q^T : D row = kv, col = q
                f32x16 s = {};
                #pragma unroll
                for (int k8 = 0; k8 < 8; ++k8) {
                    int r = sub * 32 + l31;
                    bf16x8 kf = *(const bf16x8*)&ks[r * 128 + (((k8 * 2 + l5) ^ (r & 7)) << 3)];
                    s = __builtin_amdgcn_mfma_f32_32x32x16_bf16(kf, qf[k8], s, 0, 0, 0);
                }
                // causal mask: kv = kvs + (r&3)+8*(r>>2)+4*l5 ; q = qw0 + l31
                if (kvs + 31 > qw0) {
                    #pragma unroll
                    for (int r = 0; r < 16; ++r) {
                        int kv = kvs + (r & 3) + ((r >> 2) << 3) + l5 * 4;
                        if (kv > qw0 + l31) s[r] = -1e30f;
                    }
                }
                // online softmax, q-local (1 cross-lane op)
                float mx = s[0];
                #pragma unroll
                for (int r = 1; r < 16; ++r) mx = fmaxf(mx, s[r]);
                mx = fmaxf(mx, __shfl_xor(mx, 32));
                bool need = mx > m_run + 8.0f;   // defer-max, log2 domain
                if (__any((int)need)) {
                    float mn = fmaxf(m_run, mx);
                    float al = exp2f(m_run - mn);
                    m_run = mn;
                    l_run *= al;
                    #pragma unroll
                    for (int r = 0; r < 16; ++r) {
                        int qlr = (r & 3) + ((r >> 2) << 3) + l5 * 4;
                        float alO = __shfl(al, qlr, 32);
                        #pragma unroll
                        for (int t32 = 0; t32 < 4; ++t32) o_acc[t32][r] *= alO;
                    }
                }
                #pragma unroll
                for (int r = 0; r < 16; ++r) {
                    float p = exp2f(s[r] - m_run);
                    l_run += p;
                    s[r] = p;
                }
                // pack P -> A-frags: bit5 exchange only
                bf16x8 pa[2];
                #pragma unroll
                for (int kk1 = 0; kk1 < 2; ++kk1) {
                    unsigned u0 = cvtpk(s[kk1 * 8 + 0], s[kk1 * 8 + 1]);
                    unsigned u1 = cvtpk(s[kk1 * 8 + 2], s[kk1 * 8 + 3]);
                    unsigned u2 = cvtpk(s[kk1 * 8 + 4], s[kk1 * 8 + 5]);
                    unsigned u3 = cvtpk(s[kk1 * 8 + 6], s[kk1 * 8 + 7]);
                    unsigned t0 = (unsigned)__shfl_xor((int)(l5 ? u0 : u2), 32);
                    unsigned t1 = (unsigned)__shfl_xor((int)(l5 ? u1 : u3), 32);
                    int4v w;
                    w.x = (int)(l5 ? t0 : u0);
                    w.y = (int)(l5 ? t1 : u1);
                    w.z = (int)(l5 ? u2 : t0);
                    w.w = (int)(l5 ? u3 : t1);
                    pa[kk1] = __builtin_bit_cast(bf16x8, w);
                }
                // PV: B-frag = vt[d = t32*32+l31][kv = sub*32 + kk1*16 + l5*8 ..]
                #pragma unroll
                for (int t32 = 0; t32 < 4; ++t32) {
                    #pragma unroll
                    for (int kk1 = 0; kk1 < 2; ++kk1) {
                        const unsigned short* vrow =
                            &vt[t32 * 32 + l31][sub * 32 + kk1 * 16 + l5 * 8];
                        int4v w;
                        w.x = *(const int*)&vrow[0];
                        w.y = *(const int*)&vrow[2];
                        w.z = *(const int*)&vrow[4];
                        w.w = *(const int*)&vrow[6];
                        o_acc[t32] = __builtin_amdgcn_mfma_f32_32x32x16_bf16(
                            pa[kk1], __builtin_bit_cast(bf16x8, w), o_acc[t32], 0, 0, 0);
                    }
                }
            }
        }
        __syncthreads();
    }

    // epilogue: l over lane-halves, redistribute to O layout, store
    float l_tot = l_run + __shfl_xor(l_run, 32);
    float rinv = __builtin_amdgcn_rcpf(l_tot);
    #pragma unroll
    for (int r = 0; r < 16; ++r) {
        int qlr = (r & 3) + ((r >> 2) << 3) + l5 * 4;
        float rl = __shfl(rinv, qlr, 32);
        #pragma unroll
        for (int t32 = 0; t32 < 4; ++t32)
            O[(size_t)(qw0 + qlr) * DIM + h * HD + t32 * 32 + l31] =
                f2bf(o_acc[t32][r] * rl);
    }
}

// ---------------- host ----------------
extern "C" void kernel_launch(void* const* d_in, const int* in_sizes, int n_in,
                              void* d_out, int out_size, void* d_ws, size_t ws_size,
                              hipStream_t stream) {
    const float* x  = (const float*)d_in[0];
    const float* wq = (const float*)d_in[2];
    const float* wk = (const float*)d_in[3];
    const float* wv = (const float*)d_in[4];
    const float* wo = (const float*)d_in[5];
    float* out = (float*)d_out;

    char* ws = (char*)d_ws;
    unsigned short* xb  = (unsigned short*)(ws);               // 16 MiB
    unsigned short* qb  = (unsigned short*)(ws + 16777216);    // 16 MiB
    unsigned short* kvb = (unsigned short*)(ws + 33554432);    //  8 MiB (K|V, stride 2048)
    unsigned short* ab  = (unsigned short*)(ws + 41943040);    // 16 MiB
    float* cs = (float*)(ws + 58720256);
    float* sn = cs + SEQ * 64;
    unsigned short* wscratch = (unsigned short*)d_out;         // weight staging
    unsigned short* wob = (unsigned short*)(ws);               // after attn: xb dead

    const float SCALE2 = 0.08838834764831845f * 1.4426950408889634f;

    convert_f32_bf16<<<SEQ * DIM / 2048, 256, 0, stream>>>(x, xb, SEQ * DIM);
    rope_table<<<SEQ * 64 / 256, 256, 0, stream>>>(cs, sn);

    convert_f32_bf16<<<DIM * DIM / 2048, 256, 0, stream>>>(wq, wscratch, DIM * DIM);
    gemm_bt<true><<<dim3(DIM / 128, SEQ / 128), 256, 0, stream>>>(xb, wscratch, qb, SEQ, DIM, DIM);

    convert_f32_bf16<<<KVDIM * DIM / 2048, 256, 0, stream>>>(wk, wscratch, KVDIM * DIM);
    convert_f32_bf16<<<KVDIM * DIM / 2048, 256, 0, stream>>>(wv, wscratch + (size_t)KVDIM * DIM, KVDIM * DIM);
    gemm_bt<true><<<dim3(KVSTRIDE / 128, SEQ / 128), 256, 0, stream>>>(xb, wscratch, kvb, SEQ, KVSTRIDE, DIM);

    rope_apply<<<SEQ * (DIM / 2) / 256, 256, 0, stream>>>(qb, 11, DIM, SCALE2, cs, sn);
    rope_apply<<<SEQ * (KVDIM / 2) / 256, 256, 0, stream>>>(kvb, 9, KVSTRIDE, 1.0f, cs, sn);

    attn_kernel<<<dim3(HEADS, SEQ / 128), 256, 0, stream>>>(qb, kvb, ab);

    convert_f32_bf16<<<DIM * DIM / 2048, 256, 0, stream>>>(wo, wob, DIM * DIM);
    gemm_bt<false><<<dim3(DIM / 128, SEQ / 128), 256, 0, stream>>>(ab, wob, out, SEQ, DIM, DIM);
}